// Round 10
// baseline (256.579 us; speedup 1.0000x reference)
//
#include <hip/hip_runtime.h>
#include <hip/hip_bf16.h>
#include <stdint.h>

// LSTM cell, FULLY FUSED single main kernel (+ weight pack):
//   pack:  weights -> bf16 MFMA-B-fragment layout (1 MB in d_ws), bias packed
//   fused: per block: 128 rows x 1024 gate cols in 4 quarter-iterations of
//          256 cols (acc[2][8] per wave). A: f32 loaded coalesced into regs,
//          cvt_pk -> bf16, swizzled ds_write_b128 into single-buffered A-LDS
//          (swizzle r16 ^= kg<<2: conflict-free write AND read). B: bf16 via
//          global_load_lds into dbuf LDS. Counted vmcnt + raw barriers.
//          Epilogue per quarter: bias+gates+cell update, write nc/nh, exp-sum
//          into LDS rowsum (atomicAdd). After 4 quarters: lz = log(rowsum),
//          re-read own nh (L2/L3-resident) and write log_softmax output.
// B=65536, IN=H=256, K=512, 4H=1024 gate cols.

#define BH 16777216  // 65536*256

typedef float f32x4 __attribute__((ext_vector_type(4)));
typedef short short8 __attribute__((ext_vector_type(8)));

__device__ __forceinline__ unsigned short f2bf(float f) {
    union { float f; unsigned u; } v; v.f = f;
    unsigned u = v.u;
    return (unsigned short)((u + 0x7fffu + ((u >> 16) & 1u)) >> 16);
}

__device__ __forceinline__ unsigned pack2bf(float a, float b) {
    __hip_bfloat162 h = __float22bfloat162_rn(make_float2(a, b));
    union { __hip_bfloat162 h; unsigned u; } v; v.h = h;
    return v.u;  // v_cvt_pk_bf16_f32
}

__device__ __forceinline__ float sigm(float x) { return 1.f / (1.f + __expf(-x)); }
__device__ __forceinline__ float tanh_(float x) { return 1.f - 2.f / (1.f + __expf(2.f * x)); }

__device__ __forceinline__ void glds16(const void* g, const void* l) {
    __builtin_amdgcn_global_load_lds(
        (const __attribute__((address_space(1))) unsigned int*)(uintptr_t)g,
        (__attribute__((address_space(3))) unsigned int*)(unsigned int)(uintptr_t)l,
        16, 0, 0);
}

// ---- pack: wpack hw idx = (((ch*16+step)*16 + Nt)*64 + l)*8 + j ----
// Nt = wc*8 + g*2 + hh (wc 0..1, g 0..3, hh 0..1);
// h = ch*64 + wc*32 + hh*16 + (l&15); k = step*32 + (l>>4)*8 + j
__global__ __launch_bounds__(256) void pack_kernel(
    const float* __restrict__ Wif, const float* __restrict__ Wii,
    const float* __restrict__ Wio, const float* __restrict__ Wig,
    const float* __restrict__ Whf, const float* __restrict__ Whi,
    const float* __restrict__ Who, const float* __restrict__ Whg,
    const float* __restrict__ bif, const float* __restrict__ bii,
    const float* __restrict__ bio, const float* __restrict__ big,
    const float* __restrict__ bhf, const float* __restrict__ bhi,
    const float* __restrict__ bho, const float* __restrict__ bhg,
    unsigned short* __restrict__ wpack, float* __restrict__ bpack)
{
    const int t = blockIdx.x * 256 + threadIdx.x;   // 0..65535
    const int l    = t & 63;
    const int Nt   = (t >> 6) & 15;
    const int step = (t >> 10) & 15;
    const int ch   = t >> 14;                        // 0..3
    const int gate = (Nt >> 1) & 3;
    const int hh   = Nt & 1;
    const int wc   = Nt >> 3;
    const int h    = ch * 64 + wc * 32 + hh * 16 + (l & 15);
    const int k0   = step * 32 + (l >> 4) * 8;

    const float* Wi = (gate == 0) ? Wif : (gate == 1) ? Wii : (gate == 2) ? Wio : Wig;
    const float* Wh = (gate == 0) ? Whf : (gate == 1) ? Whi : (gate == 2) ? Who : Whg;
    const float* src = (k0 < 256) ? (Wi + h * 256 + k0) : (Wh + h * 256 + (k0 - 256));

    unsigned pk[4];
#pragma unroll
    for (int p = 0; p < 4; ++p)
        pk[p] = (unsigned)f2bf(src[p * 2]) | ((unsigned)f2bf(src[p * 2 + 1]) << 16);
    uint4 o4 = {pk[0], pk[1], pk[2], pk[3]};
    *(uint4*)&wpack[(size_t)t * 8] = o4;

    if (t < 1024) {
        const int n2 = t & 15, Nt2 = (t >> 4) & 15, ch2 = t >> 8;
        const int g2 = (Nt2 >> 1) & 3, hh2 = Nt2 & 1, wc2 = Nt2 >> 3;
        const int h2 = ch2 * 64 + wc2 * 32 + hh2 * 16 + n2;
        const float* bi = (g2 == 0) ? bif : (g2 == 1) ? bii : (g2 == 2) ? bio : big;
        const float* bh = (g2 == 0) ? bhf : (g2 == 1) ? bhi : (g2 == 2) ? bho : bhg;
        bpack[t] = bi[h2] + bh[h2];
    }
}

// ---- fused main kernel: grid 512 (one per 128-row panel), block 512 ----
__global__ __launch_bounds__(512, 4) void lstm_fused_kernel(
    const float* __restrict__ input, const float* __restrict__ hidden,
    const float* __restrict__ cell,
    const unsigned short* __restrict__ wpack, const float* __restrict__ bpack,
    float* __restrict__ out)
{
    __shared__ unsigned short Ab[4096];      // 8 KB, single-buffered A (swizzled)
    __shared__ unsigned short Bb[2][8192];   // 2 x 16 KB, dbuf B
    __shared__ float rowsum[128];            // exp-sums, then lz in-place

    const int panel = blockIdx.x;
    const int row0  = panel * 128;
    const int tid = threadIdx.x;
    const int w = tid >> 6, l = tid & 63;
    const int wr = w >> 1, wc = w & 1;       // wave = 32 rows x 128 cols
    const int n16 = l & 15, lrow = l >> 4;   // lrow == kg for A-frag reads

    if (tid < 128) rowsum[tid] = 0.f;

    // A staging: thread -> (row = tid>>2, kg = tid&3), loads 8 f32, writes 16B
    const int arow = tid >> 2;
    const int akg  = tid & 3;
    const int art = arow >> 4, ar16 = arow & 15;
    const int awhw = (art * 64 + akg * 16 + (ar16 ^ (akg << 2))) * 8;
    const size_t aoff = (size_t)(row0 + arow) * 256 + akg * 8;

#pragma unroll 1
    for (int ch = 0; ch < 4; ++ch) {
        const unsigned short* wsrc = wpack + (size_t)ch * 131072;

        // ---- prologue: A0 + B0 ----
        {
            float4 v0 = *(const float4*)(input + aoff);
            float4 v1 = *(const float4*)(input + aoff + 4);
            glds16(wsrc + (size_t)(w * 2)     * 512 + l * 8, &Bb[0][(w * 2) * 512]);
            glds16(wsrc + (size_t)(w * 2 + 1) * 512 + l * 8, &Bb[0][(w * 2 + 1) * 512]);
            uint4 aw;
            aw.x = pack2bf(v0.x, v0.y); aw.y = pack2bf(v0.z, v0.w);
            aw.z = pack2bf(v1.x, v1.y); aw.w = pack2bf(v1.z, v1.w);
            *(uint4*)&Ab[awhw] = aw;
        }
        __syncthreads();   // drains all vmem + lds; Ab/Bb[0] ready

        f32x4 acc[2][8] = {};

#pragma unroll 1
        for (int k = 0; k < 16; ++k) {
            const int cb = k & 1, nb = cb ^ 1;
            float4 nv0, nv1;
            if (k < 15) {
                const int kn = (k + 1) * 32;
                const float* xb = (kn < 256) ? (input + kn) : (hidden + (kn - 256));
                nv0 = *(const float4*)(xb + aoff);
                nv1 = *(const float4*)(xb + aoff + 4);
                glds16(wsrc + ((size_t)(k + 1) * 16 + w * 2)     * 512 + l * 8,
                       &Bb[nb][(w * 2) * 512]);
                glds16(wsrc + ((size_t)(k + 1) * 16 + w * 2 + 1) * 512 + l * 8,
                       &Bb[nb][(w * 2 + 1) * 512]);
            }
            short8 Af[2], Bf[8];
#pragma unroll
            for (int m = 0; m < 2; ++m)
                Af[m] = *(const short8*)&Ab[((wr * 2 + m) * 64 + lrow * 16
                                             + (n16 ^ (lrow << 2))) * 8];
#pragma unroll
            for (int n = 0; n < 8; ++n)
                Bf[n] = *(const short8*)&Bb[cb][((wc * 8 + n) * 64 + l) * 8];

            __builtin_amdgcn_s_setprio(1);
#pragma unroll
            for (int m = 0; m < 2; ++m)
#pragma unroll
                for (int n = 0; n < 8; ++n)
                    acc[m][n] = __builtin_amdgcn_mfma_f32_16x16x32_bf16(
                        Af[m], Bf[n], acc[m][n], 0, 0, 0);
            __builtin_amdgcn_s_setprio(0);

            __builtin_amdgcn_s_barrier();   // e: all reads of Ab/Bb[cb] done

            if (k < 15) {
                asm volatile("s_waitcnt vmcnt(2)" ::: "memory");  // A f32 landed
                uint4 aw;
                aw.x = pack2bf(nv0.x, nv0.y); aw.y = pack2bf(nv0.z, nv0.w);
                aw.z = pack2bf(nv1.x, nv1.y); aw.w = pack2bf(nv1.z, nv1.w);
                *(uint4*)&Ab[awhw] = aw;
                asm volatile("s_waitcnt vmcnt(0) lgkmcnt(0)" ::: "memory");
            }
            __builtin_amdgcn_s_barrier();   // h: Ab(k+1) + Bb[nb] published
        }

        // ---- epilogue for this quarter: gates + cell + rowsum ----
        float bias[8];
#pragma unroll
        for (int n = 0; n < 8; ++n)
            bias[n] = bpack[ch * 256 + (wc * 8 + n) * 16 + n16];

#pragma unroll
        for (int m = 0; m < 2; ++m) {
#pragma unroll
            for (int rr = 0; rr < 4; ++rr) {
                const int rloc = wr * 32 + m * 16 + lrow * 4 + rr;
                const size_t rg_ = (size_t)row0 + rloc;
                float s = 0.f;
#pragma unroll
                for (int hh = 0; hh < 2; ++hh) {
                    const float fv = sigm(acc[m][0 + hh][rr] + bias[0 + hh]);
                    const float iv = sigm(acc[m][2 + hh][rr] + bias[2 + hh]);
                    const float ov = sigm(acc[m][4 + hh][rr] + bias[4 + hh]);
                    const float gv = tanh_(acc[m][6 + hh][rr] + bias[6 + hh]);
                    const int hcol = ch * 64 + wc * 32 + hh * 16 + n16;
                    const float cv = cell[rg_ * 256 + hcol];
                    const float nc = fv * cv + iv * gv;
                    const float nhv = ov * tanh_(nc);
                    out[(size_t)2 * BH + rg_ * 256 + hcol] = nc;
                    out[(size_t)BH + rg_ * 256 + hcol] = nhv;
                    s += __expf(nhv);
                }
#pragma unroll
                for (int msk = 1; msk < 16; msk <<= 1)
                    s += __shfl_xor(s, msk);
                if (n16 == 0) atomicAdd(&rowsum[rloc], s);
            }
        }
        // next quarter's prologue __syncthreads() orders everything
    }

    __syncthreads();   // all rowsum adds done; nh stores drained (vmcnt 0)
    if (tid < 128) rowsum[tid] = __logf(rowsum[tid]);
    __syncthreads();

    // ---- final pass: out[row][h] = nh - lz, nh re-read from L2/L3 ----
#pragma unroll 1
    for (int it = 0; it < 16; ++it) {
        const int flat = it * 2048 + tid * 4;       // 0..32767
        const int rw = flat >> 8;
        const int hc = flat & 255;
        const float lz = rowsum[rw];
        float4 v = *(const float4*)(out + (size_t)BH + (size_t)(row0 + rw) * 256 + hc);
        float4 o = {v.x - lz, v.y - lz, v.z - lz, v.w - lz};
        *(float4*)(out + (size_t)(row0 + rw) * 256 + hc) = o;
    }
}

extern "C" void kernel_launch(void* const* d_in, const int* in_sizes, int n_in,
                              void* d_out, int out_size, void* d_ws, size_t ws_size,
                              hipStream_t stream)
{
    const float* input  = (const float*)d_in[0];
    const float* hidden = (const float*)d_in[1];
    const float* cell   = (const float*)d_in[2];
    const float* Wif = (const float*)d_in[3];  const float* bif = (const float*)d_in[4];
    const float* Wii = (const float*)d_in[5];  const float* bii = (const float*)d_in[6];
    const float* Wio = (const float*)d_in[7];  const float* bio = (const float*)d_in[8];
    const float* Wig = (const float*)d_in[9];  const float* big = (const float*)d_in[10];
    const float* Whf = (const float*)d_in[11]; const float* bhf = (const float*)d_in[12];
    const float* Whi = (const float*)d_in[13]; const float* bhi = (const float*)d_in[14];
    const float* Who = (const float*)d_in[15]; const float* bho = (const float*)d_in[16];
    const float* Whg = (const float*)d_in[17]; const float* bhg = (const float*)d_in[18];

    unsigned short* wpack = (unsigned short*)d_ws;                 // 1 MB
    float* bpack = (float*)((char*)d_ws + (size_t)1024 * 512 * 2); // 4 KB

    float* out = (float*)d_out;

    hipLaunchKernelGGL(pack_kernel, dim3(256), dim3(256), 0, stream,
        Wif, Wii, Wio, Wig, Whf, Whi, Who, Whg,
        bif, bii, bio, big, bhf, bhi, bho, bhg, wpack, bpack);

    hipLaunchKernelGGL(lstm_fused_kernel, dim3(512), dim3(512), 0, stream,
        input, hidden, cell, wpack, bpack, out);
}